// Round 5
// baseline (4666.829 us; speedup 1.0000x reference)
//
#include <hip/hip_runtime.h>
#include <hip/hip_bf16.h>
#include <hip/hip_fp16.h>

#define NN 4096
#define NGROW 8
#define NPOL 2
#define NITER (NGROW + NPOL)
#define NPOW 12
#define NTRI 528          // 32*33/2 lower-triangle 128-tiles
#define KHALF 2048
#define PRESCALE 32.0f    // keeps pre-rescale A entries in f16 normal range

using f16 = _Float16;
typedef __attribute__((ext_vector_type(4))) float f32x4;
typedef __attribute__((ext_vector_type(8))) f16 h16x8;

// ---------------------------------------------------------------------------
// async global->LDS, 16B per lane. LDS side MUST be wave-uniform base + lane*16.
// ---------------------------------------------------------------------------
__device__ inline void gl_lds16(const void* g, void* l) {
  __builtin_amdgcn_global_load_lds(
      (const __attribute__((address_space(1))) unsigned int*)(unsigned long long)(uintptr_t)g,
      (__attribute__((address_space(3))) unsigned int*)(uintptr_t)l,
      16, 0, 0);
}

__device__ inline void tri_decode(int t, int& bi, int& bj) {
  int r = (int)((sqrtf(8.0f * (float)t + 1.0f) - 1.0f) * 0.5f);
  while ((r + 1) * (r + 2) / 2 <= t) ++r;
  while (r * (r + 1) / 2 > t) --r;
  bi = r;
  bj = t - r * (r + 1) / 2;
}

// ---------------------------------------------------------------------------
// NT GEMM: C[i,j] = sum_k P[i,k] * Q[j,k]  (row-major f16, 4096^2)
// MODE 0: full grid (32,32), out = alpha*aux + beta*acc -> f16
// MODE 1: same, fp32 out
// MODE 2: tri K-split. grid (528, 2); blockIdx.y = K-half.
//         half0 -> compact fp32 p0[tile][128][128] (NO rounding);
//         half1 -> raw f16 at straight dest position.
//         combine_tri later sums halves + epilogue + mirror.
// ---------------------------------------------------------------------------
template <int MODE>
__global__ __launch_bounds__(256, 4) void gemm_nt(
    const f16* __restrict__ P, const f16* __restrict__ Q,
    void* __restrict__ Out, const f16* __restrict__ aux,
    float alpha, float beta, float* __restrict__ p0) {
  int bi, bj, kbeg, kend;
  if (MODE == 2) {
    tri_decode(blockIdx.x, bi, bj);
    kbeg = blockIdx.y * KHALF;
    kend = kbeg + KHALF;
  } else {
    bi = blockIdx.x;
    bj = blockIdx.y;
    kbeg = 0;
    kend = NN;
  }

  __shared__ f16 lp[128 * 64];
  __shared__ f16 lq[128 * 64];

  const int tid = threadIdx.x;
  const int lane = tid & 63;
  const int wv = tid >> 6;
  const int wr = wv >> 1, wc = wv & 1;

  const int m = lane & 15;
  const int qd = lane >> 4;
  const int lrow = lane >> 3;
  const int lchunk = lane & 7;

  f32x4 acc[4][4] = {};

  for (int k0 = kbeg; k0 < kend; k0 += 64) {
    __syncthreads();
#pragma unroll
    for (int s = 0; s < 4; ++s) {
      const int t = wv * 4 + s;
      const int r = t * 8 + lrow;
      const int gc = lchunk ^ (r & 7);          // XOR swizzle (0 bank conflicts, R1)
      const f16* gp = P + (size_t)(bi * 128 + r) * NN + k0 + gc * 8;
      gl_lds16(gp, &lp[t * 512 + lane * 8]);
      const f16* gq = Q + (size_t)(bj * 128 + r) * NN + k0 + gc * 8;
      gl_lds16(gq, &lq[t * 512 + lane * 8]);
    }
    __syncthreads();

#pragma unroll
    for (int sub = 0; sub < 2; ++sub) {
      h16x8 av[4], bv[4];
#pragma unroll
      for (int f = 0; f < 4; ++f) {
        const int ra = wr * 64 + f * 16 + m;
        const int ca = (sub * 4 + qd) ^ (ra & 7);
        av[f] = *(const h16x8*)&lp[ra * 64 + ca * 8];
        const int rb = wc * 64 + f * 16 + m;
        const int cb = (sub * 4 + qd) ^ (rb & 7);
        bv[f] = *(const h16x8*)&lq[rb * 64 + cb * 8];
      }
#pragma unroll
      for (int fr = 0; fr < 4; ++fr)
#pragma unroll
        for (int fc = 0; fc < 4; ++fc)
          acc[fr][fc] = __builtin_amdgcn_mfma_f32_16x16x32_f16(
              av[fr], bv[fc], acc[fr][fc], 0, 0, 0);
    }
  }

  // C/D layout: col = lane&15, row = (lane>>4)*4 + reg  [m89/m91, dtype-indep]
#pragma unroll
  for (int fr = 0; fr < 4; ++fr) {
#pragma unroll
    for (int fc = 0; fc < 4; ++fc) {
#pragma unroll
      for (int rg = 0; rg < 4; ++rg) {
        const int lr = wr * 64 + fr * 16 + qd * 4 + rg;   // row within tile
        const int lc = wc * 64 + fc * 16 + m;             // col within tile
        if (MODE == 2) {
          if (blockIdx.y == 0)
            p0[(size_t)blockIdx.x * 16384 + lr * 128 + lc] = acc[fr][fc][rg];
          else
            ((f16*)Out)[(size_t)(bi * 128 + lr) * NN + bj * 128 + lc] =
                (f16)acc[fr][fc][rg];
        } else {
          const size_t idx = (size_t)(bi * 128 + lr) * NN + bj * 128 + lc;
          float v = beta * acc[fr][fc][rg];
          if (alpha != 0.0f) v += alpha * (float)aux[idx];
          if (MODE == 0)
            ((f16*)Out)[idx] = (f16)v;
          else
            ((float*)Out)[idx] = v;
        }
      }
    }
  }
}

// ---------------------------------------------------------------------------
// combine_tri: dest = alpha*aux + beta*(p0_fp32 + p1) over 528 lower-tri
// tiles; p1 read raw f16 from dest's straight positions; mirror tile written
// via LDS transpose (diagonal tiles: straight writes cover everything).
// ---------------------------------------------------------------------------
__global__ __launch_bounds__(256) void combine_tri(
    const float* __restrict__ p0, f16* __restrict__ dest,
    const f16* __restrict__ aux, float alpha, float beta) {
  int bi, bj;
  tri_decode(blockIdx.x, bi, bj);
  __shared__ f16 tile[64][72];
  const int rr = threadIdx.x >> 2;        // 0..63
  const int cg = (threadIdx.x & 3) * 16;  // 0/16/32/48

#pragma unroll
  for (int qr = 0; qr < 2; ++qr)
#pragma unroll
    for (int qc = 0; qc < 2; ++qc) {
      const int grow = bi * 128 + qr * 64 + rr;
      const size_t gidx = (size_t)grow * NN + bj * 128 + qc * 64 + cg;
      const size_t pidx = (size_t)blockIdx.x * 16384 + (qr * 64 + rr) * 128 + qc * 64 + cg;
      const float4 a0 = *(const float4*)(p0 + pidx);
      const float4 a1 = *(const float4*)(p0 + pidx + 4);
      const float4 a2 = *(const float4*)(p0 + pidx + 8);
      const float4 a3 = *(const float4*)(p0 + pidx + 12);
      const h16x8 b0 = *(const h16x8*)(dest + gidx);
      const h16x8 b1 = *(const h16x8*)(dest + gidx + 8);
      float v[16] = {a0.x, a0.y, a0.z, a0.w, a1.x, a1.y, a1.z, a1.w,
                     a2.x, a2.y, a2.z, a2.w, a3.x, a3.y, a3.z, a3.w};
#pragma unroll
      for (int j = 0; j < 8; ++j) {
        v[j] = beta * (v[j] + (float)b0[j]);
        v[j + 8] = beta * (v[j + 8] + (float)b1[j]);
      }
      if (alpha != 0.0f) {
        const h16x8 x0 = *(const h16x8*)(aux + gidx);
        const h16x8 x1 = *(const h16x8*)(aux + gidx + 8);
#pragma unroll
        for (int j = 0; j < 8; ++j) {
          v[j] += alpha * (float)x0[j];
          v[j + 8] += alpha * (float)x1[j];
        }
      }
      h16x8 o0, o1;
#pragma unroll
      for (int j = 0; j < 8; ++j) { o0[j] = (f16)v[j]; o1[j] = (f16)v[j + 8]; }
      *(h16x8*)(dest + gidx) = o0;
      *(h16x8*)(dest + gidx + 8) = o1;

      if (bi != bj) {  // mirror quadrant (qc,qr) of tile (bj,bi)
#pragma unroll
        for (int j = 0; j < 8; ++j) {
          tile[rr][cg + j] = o0[j];
          tile[rr][cg + 8 + j] = o1[j];
        }
        __syncthreads();
        h16x8 m0, m1;
#pragma unroll
        for (int j = 0; j < 8; ++j) {
          m0[j] = tile[cg + j][rr];
          m1[j] = tile[cg + 8 + j][rr];
        }
        const size_t tidx = (size_t)(bj * 128 + qc * 64 + rr) * NN + bi * 128 + qr * 64 + cg;
        *(h16x8*)(dest + tidx) = m0;
        *(h16x8*)(dest + tidx + 8) = m1;
        __syncthreads();  // tile reused next quadrant
      }
    }
}

// ---------------------------------------------------------------------------
// 2-byte transpose, 64x64 LDS tiles (pad +1 to break bank conflicts)
// ---------------------------------------------------------------------------
__global__ void transpose_h(const unsigned short* __restrict__ in,
                            unsigned short* __restrict__ out) {
  __shared__ unsigned short tile[64][65];
  const int tx = threadIdx.x & 63;
  const int ty = threadIdx.x >> 6;
  const int bx = blockIdx.x, by = blockIdx.y;
#pragma unroll
  for (int rr = 0; rr < 16; ++rr) {
    const int row = rr * 4 + ty;
    tile[row][tx] = in[(size_t)(by * 64 + row) * NN + bx * 64 + tx];
  }
  __syncthreads();
#pragma unroll
  for (int rr = 0; rr < 16; ++rr) {
    const int row = rr * 4 + ty;
    out[(size_t)(bx * 64 + row) * NN + by * 64 + tx] = tile[tx][row];
  }
}

// ---------------------------------------------------------------------------
// Power iteration matvec on symmetric f16 A: vout = A*(vin*rsqrt(*snin)),
// atomicAdd ||vout||^2 into *snout. One wave per row.
// ---------------------------------------------------------------------------
__global__ __launch_bounds__(256) void powmv(const f16* __restrict__ A,
                                             const float* __restrict__ vin,
                                             const float* __restrict__ snin,
                                             float* __restrict__ vout,
                                             float* __restrict__ snout) {
  const float scale = rsqrtf(*snin);
  const int row = blockIdx.x * 4 + (threadIdx.x >> 6);
  const int lane = threadIdx.x & 63;
  const f16* arow = A + (size_t)row * NN;
  float acc = 0.0f;
#pragma unroll
  for (int p = 0; p < 8; ++p) {
    const int c = p * 512 + lane * 8;
    const h16x8 av = *(const h16x8*)(arow + c);
    const float4 w0 = *(const float4*)(vin + c);
    const float4 w1 = *(const float4*)(vin + c + 4);
    acc += (float)av[0] * w0.x + (float)av[1] * w0.y + (float)av[2] * w0.z +
           (float)av[3] * w0.w + (float)av[4] * w1.x + (float)av[5] * w1.y +
           (float)av[6] * w1.z + (float)av[7] * w1.w;
  }
  for (int off = 32; off; off >>= 1) acc += __shfl_down(acc, off, 64);
  if (lane == 0) {
    const float u = acc * scale;
    vout[row] = u;
    atomicAdd(snout, u * u);
  }
}

// ---------------------------------------------------------------------------
// init: slots[64] (slot1=1 for ||v0||^2), v0 = +-1/64
// ---------------------------------------------------------------------------
__global__ void init_pw(float* __restrict__ v0, float* __restrict__ slots) {
  const int t = threadIdx.x;
  if (t < 64) slots[t] = (t == 1) ? 1.0f : 0.0f;
  for (int i = t; i < NN; i += 256) {
    const unsigned h = (unsigned)i * 2654435761u;
    v0[i] = ((h >> 16) & 1) ? 0.015625f : -0.015625f;
  }
}

// ---------------------------------------------------------------------------
// ||H||_F^2 -> slots[0]
// ---------------------------------------------------------------------------
__global__ void reduce_sumsq(const float* __restrict__ h, float* __restrict__ slots) {
  float acc = 0.0f;
  const size_t total = (size_t)NN * NN;
  for (size_t i = (size_t)blockIdx.x * blockDim.x + threadIdx.x; i < total;
       i += (size_t)gridDim.x * blockDim.x) {
    const float v = h[i];
    acc += v * v;
  }
  for (int off = 32; off; off >>= 1) acc += __shfl_down(acc, off, 64);
  __shared__ float ws[4];
  const int lane = threadIdx.x & 63, wv = threadIdx.x >> 6;
  if (lane == 0) ws[wv] = acc;
  __syncthreads();
  if (threadIdx.x == 0) atomicAdd(&slots[0], ws[0] + ws[1] + ws[2] + ws[3]);
}

// ---------------------------------------------------------------------------
// H (fp32) -> f16, scaled.
//   mode 0: X0' = H * PRESCALE / ||H||_F          (pre-scale for lambda est)
//   mode 1: X0  = H * PRESCALE / (||H||_F * sqrt(1.10*lam_hat))
//   lam_hat = sqrt(slots[1+NPOW]) ~ lambda_max(A')  (power iteration)
// ---------------------------------------------------------------------------
__global__ void scale_cast(const float* __restrict__ h, const float* __restrict__ slots,
                           f16* __restrict__ xb, int mode) {
  float inv = rsqrtf(slots[0]) * PRESCALE;
  if (mode) inv *= rsqrtf(1.10f * sqrtf(slots[1 + NPOW]));
  const size_t i = ((size_t)blockIdx.x * blockDim.x + threadIdx.x) * 4;
  const float4 v = *(const float4*)(h + i);
  union { f16 hh[4]; ushort4 u; } cvt;
  cvt.hh[0] = (f16)(v.x * inv);
  cvt.hh[1] = (f16)(v.y * inv);
  cvt.hh[2] = (f16)(v.z * inv);
  cvt.hh[3] = (f16)(v.w * inv);
  *(ushort4*)(xb + i) = cvt.u;
}

// ---------------------------------------------------------------------------
// A *= 1/(1.10*lam_hat)  so A0 = X0^T X0 for the mode-1-scaled X0.
// ---------------------------------------------------------------------------
__global__ void rescale_f16(f16* __restrict__ a, const float* __restrict__ slots) {
  const float cA = 1.0f / (1.10f * sqrtf(slots[1 + NPOW]));
  const size_t i = ((size_t)blockIdx.x * 256 + threadIdx.x) * 8;
  h16x8 v = *(h16x8*)(a + i);
  h16x8 o;
#pragma unroll
  for (int j = 0; j < 8; ++j) o[j] = (f16)((float)v[j] * cA);
  *(h16x8*)(a + i) = o;
}

// ---------------------------------------------------------------------------
// Polar factor: sigma_max-normalized quintic Newton-Schulz, f16 GEMMs.
//   8x Muon growth + 2x tangent polish (15/8,-5/4,3/8).   [R3 schedule]
//   A and B via K-split(2) tri GEMMs: half0 partial fp32 (exact), half1 raw
//   f16 at dest; combine fuses sum+epilogue+mirror.
// Buffer roles (3x 32Mi in ws): X alternates P0<->Ab slot; X^T and B share P1
//   (X^T dies exactly when B is born); A takes the non-X slot.
//   d_out: fp32 partial [0,33Mi) (dead whenever combine runs on ws buffers);
//   v0/v1/slots at +60Mi (preamble only). Final fp32 out overwrites d_out
//   after all partial reads are done.
// ---------------------------------------------------------------------------
extern "C" void kernel_launch(void* const* d_in, const int* in_sizes, int n_in,
                              void* d_out, int out_size, void* d_ws, size_t ws_size,
                              hipStream_t stream) {
  (void)in_sizes; (void)n_in; (void)out_size; (void)ws_size;
  const float* H = (const float*)d_in[0];
  float* out = (float*)d_out;
  char* ws = (char*)d_ws;

  f16* P0 = (f16*)ws;
  f16* P1 = (f16*)(ws + ((size_t)32 << 20));   // X^T / B
  f16* Ab = (f16*)(ws + ((size_t)64 << 20));
  float* pf = (float*)d_out;                    // fp32 half0 partial, 33Mi
  float* v0 = (float*)((char*)d_out + ((size_t)60 << 20));
  float* v1 = v0 + 4096;
  float* slots = v1 + 4096;

  const dim3 gfull(32, 32), gsplit(NTRI, 2), tb(256), gt(64, 64);

  // --- preamble: Frobenius scale, A0' = X0'^T X0', power-iterate lambda_max ---
  init_pw<<<1, 256, 0, stream>>>(v0, slots);
  reduce_sumsq<<<1024, 256, 0, stream>>>(H, slots);
  scale_cast<<<(NN * (size_t)NN) / 4 / 256, 256, 0, stream>>>(H, slots, P0, 0);
  transpose_h<<<gt, tb, 0, stream>>>((const unsigned short*)P0, (unsigned short*)P1);
  gemm_nt<2><<<gsplit, tb, 0, stream>>>(P1, P1, Ab, nullptr, 0.0f, 0.0f, pf);
  combine_tri<<<NTRI, tb, 0, stream>>>(pf, Ab, nullptr, 0.0f, 1.0f);
  for (int k = 0; k < NPOW; ++k) {
    const float* vi = (k & 1) ? v1 : v0;
    float* vo = (k & 1) ? v0 : v1;
    powmv<<<1024, 256, 0, stream>>>(Ab, vi, &slots[1 + k], vo, &slots[2 + k]);
  }
  rescale_f16<<<(NN * (size_t)NN) / 8 / 256, 256, 0, stream>>>(Ab, slots);
  scale_cast<<<(NN * (size_t)NN) / 4 / 256, 256, 0, stream>>>(H, slots, P0, 1);

  // --- quintic iterations ---
  f16* X = P0;   // current X; alternates with the A slot
  f16* Aslot = Ab;  // where A lives this iteration (preamble filled Ab)
  const float GA = 3.4445f, GB = -4.7750f, GC = 2.0315f;  // Muon growth
  const float PA = 1.875f, PB = -1.25f, PC = 0.375f;       // tangent polish

  for (int it = 0; it < NITER; ++it) {
    const bool polish = it >= NGROW;
    const bool last = (it == NITER - 1);
    const float qa = polish ? PA : GA, qb = polish ? PB : GB, qc = polish ? PC : GC;

    if (it > 0) {  // iteration 0 reuses the preamble's (rescaled) A
      transpose_h<<<gt, tb, 0, stream>>>((const unsigned short*)X, (unsigned short*)P1);
      gemm_nt<2><<<gsplit, tb, 0, stream>>>(P1, P1, Aslot, nullptr, 0.0f, 0.0f, pf);
      combine_tri<<<NTRI, tb, 0, stream>>>(pf, Aslot, nullptr, 0.0f, 1.0f);
    }
    // B = qb*A + qc*A*A -> P1 (X^T dead now)
    gemm_nt<2><<<gsplit, tb, 0, stream>>>(Aslot, Aslot, P1, nullptr, 0.0f, 0.0f, pf);
    combine_tri<<<NTRI, tb, 0, stream>>>(pf, P1, Aslot, qb, qc);
    if (!last) {
      // X' = qa*X + X*B -> Aslot (A dead after combine consumed it as aux)
      gemm_nt<0><<<gfull, tb, 0, stream>>>(X, P1, Aslot, X, qa, 1.0f, nullptr);
      f16* t = X; X = Aslot; Aslot = t;
    } else {
      gemm_nt<1><<<gfull, tb, 0, stream>>>(X, P1, out, X, qa, 1.0f, nullptr);
    }
  }
}